// Round 1
// baseline (3030.495 us; speedup 1.0000x reference)
//
#include <hip/hip_runtime.h>
#include <math.h>

#define HD 64
#define NEGS 0.1f
#define CHUNK 2048

__device__ __forceinline__ float leaky(float v) { return v > 0.f ? v : NEGS * v; }

__global__ void zero_i32(int* __restrict__ p, int n) {
    int i = blockIdx.x * blockDim.x + threadIdx.x;
    int stride = gridDim.x * blockDim.x;
    for (; i < n; i += stride) p[i] = 0;
}

// One wave per node; lane = output feature. 2-layer MLP encoder.
template <int IN>
__global__ void encode_k(const float* __restrict__ x,
                         const float* __restrict__ W1, const float* __restrict__ b1,
                         const float* __restrict__ W2, const float* __restrict__ b2,
                         float* __restrict__ out, int n) {
    __shared__ float sW2[HD * HD];
    for (int idx = threadIdx.x; idx < HD * HD; idx += blockDim.x) sW2[idx] = W2[idx];
    __syncthreads();
    int wave = threadIdx.x >> 6, lane = threadIdx.x & 63;
    int i = blockIdx.x * 4 + wave;
    if (i >= n) return;
    float h1 = b1[lane];
#pragma unroll
    for (int d = 0; d < IN; ++d) h1 += x[i * IN + d] * W1[d * HD + lane];
    h1 = leaky(h1);
    float h2 = b2[lane];
#pragma unroll
    for (int k = 0; k < HD; ++k) {
        float hk = __shfl(h1, k);
        h2 += hk * sW2[k * HD + lane];
    }
    out[i * HD + lane] = leaky(h2);
}

__global__ void gather_k(const float* __restrict__ enc, const int* __restrict__ ptv,
                         float* __restrict__ out, int n) {
    int idx = blockIdx.x * blockDim.x + threadIdx.x;
    int stride = gridDim.x * blockDim.x;
    int total = n * HD;
    for (; idx < total; idx += stride) {
        int i = idx >> 6, j = idx & 63;
        out[idx] = enc[ptv[i] * HD + j];
    }
}

__global__ void hist_k(const int* __restrict__ dst, int* __restrict__ counts, int E_) {
    for (int e = blockIdx.x * blockDim.x + threadIdx.x; e < E_; e += gridDim.x * blockDim.x)
        atomicAdd(&counts[dst[e]], 1);
}

__global__ void scan1(const int* __restrict__ counts, int* __restrict__ bsum, int n) {
    __shared__ int s[256];
    int b = blockIdx.x, t = threadIdx.x;
    int base = b * CHUNK + t * 8;
    int sum = 0;
#pragma unroll
    for (int u = 0; u < 8; ++u) {
        int i = base + u;
        if (i < n) sum += counts[i];
    }
    s[t] = sum;
    __syncthreads();
    for (int off = 128; off > 0; off >>= 1) {
        if (t < off) s[t] += s[t + off];
        __syncthreads();
    }
    if (t == 0) bsum[b] = s[0];
}

__global__ void scan2(int* __restrict__ bsum, int nb, int* __restrict__ row_ptr, int n) {
    if (threadIdx.x == 0 && blockIdx.x == 0) {
        int run = 0;
        for (int b = 0; b < nb; ++b) {
            int v = bsum[b];
            bsum[b] = run;
            run += v;
        }
        row_ptr[n] = run;
    }
}

__global__ void scan3(const int* __restrict__ counts, const int* __restrict__ bsum,
                      int* __restrict__ row_ptr, int* __restrict__ pos, int n) {
    __shared__ int s[256];
    int b = blockIdx.x, t = threadIdx.x;
    int base = b * CHUNK + t * 8;
    int c[8];
    int sum = 0;
#pragma unroll
    for (int u = 0; u < 8; ++u) {
        int i = base + u;
        c[u] = (i < n) ? counts[i] : 0;
        sum += c[u];
    }
    s[t] = sum;
    __syncthreads();
    // inclusive Hillis-Steele scan over thread sums
    for (int off = 1; off < 256; off <<= 1) {
        int v = (t >= off) ? s[t - off] : 0;
        __syncthreads();
        s[t] += v;
        __syncthreads();
    }
    int run = bsum[b] + s[t] - sum;  // exclusive prefix for this thread
#pragma unroll
    for (int u = 0; u < 8; ++u) {
        int i = base + u;
        if (i < n) {
            row_ptr[i] = run;
            pos[i] = run;
            run += c[u];
        }
    }
}

__global__ void scatter_k(const int* __restrict__ src, const int* __restrict__ dst,
                          int* __restrict__ pos, int* __restrict__ col, int E_) {
    for (int e = blockIdx.x * blockDim.x + threadIdx.x; e < E_; e += gridDim.x * blockDim.x) {
        int d = dst[e];
        int p = atomicAdd(&pos[d], 1);
        col[p] = src[e];
    }
}

// One wave per node: lane = feature. agg = sum_{src in N(i)} hin[src];
// out = leaky(agg @ Wl + hin[i] @ Wr + b)
__global__ void sage_hidden(const float* __restrict__ hin, float* __restrict__ hout,
                            const int* __restrict__ row_ptr, const int* __restrict__ col,
                            const float* __restrict__ Wl, const float* __restrict__ Wr,
                            const float* __restrict__ bias, int n) {
    __shared__ float sWl[HD * HD];
    __shared__ float sWr[HD * HD];
    for (int idx = threadIdx.x; idx < HD * HD; idx += blockDim.x) {
        sWl[idx] = Wl[idx];
        sWr[idx] = Wr[idx];
    }
    __syncthreads();
    int wave = threadIdx.x >> 6, lane = threadIdx.x & 63;
    int nw = gridDim.x * 4;
    for (int i = blockIdx.x * 4 + wave; i < n; i += nw) {
        int s = row_ptr[i], e = row_ptr[i + 1];
        float acc = 0.f;
        for (int k = s; k < e; ++k) acc += hin[col[k] * HD + lane];
        float hs = hin[i * HD + lane];
        float o = bias[lane];
#pragma unroll
        for (int k = 0; k < HD; ++k) {
            float ak = __shfl(acc, k);
            float hk = __shfl(hs, k);
            o += ak * sWl[k * HD + lane] + hk * sWr[k * HD + lane];
        }
        hout[i * HD + lane] = leaky(o);
    }
}

__global__ void sage_last(const float* __restrict__ hin, float* __restrict__ out,
                          const int* __restrict__ row_ptr, const int* __restrict__ col,
                          const float* __restrict__ Wl, const float* __restrict__ Wr,
                          const float* __restrict__ bias, int n) {
    int wave = threadIdx.x >> 6, lane = threadIdx.x & 63;
    float wl = Wl[lane], wr = Wr[lane];
    float b0 = bias[0];
    int nw = gridDim.x * 4;
    for (int i = blockIdx.x * 4 + wave; i < n; i += nw) {
        int s = row_ptr[i], e = row_ptr[i + 1];
        float acc = 0.f;
        for (int k = s; k < e; ++k) acc += hin[col[k] * HD + lane];
        float hs = hin[i * HD + lane];
        float v = acc * wl + hs * wr;
#pragma unroll
        for (int off = 32; off > 0; off >>= 1) v += __shfl_xor(v, off);
        if (lane == 0) out[i] = 1.f / (1.f + expf(-(v + b0)));
    }
}

extern "C" void kernel_launch(void* const* d_in, const int* in_sizes, int n_in,
                              void* d_out, int out_size, void* d_ws, size_t ws_size,
                              hipStream_t stream) {
    const float* x_gen = (const float*)d_in[0];
    const float* x_load = (const float*)d_in[1];
    const float* x_or = (const float*)d_in[2];
    const float* x_ex = (const float*)d_in[3];
    const int* edge = (const int*)d_in[4];
    const int* ptv = (const int*)d_in[5];
    const float* W_gen1 = (const float*)d_in[6];
    const float* b_gen1 = (const float*)d_in[7];
    const float* W_gen2 = (const float*)d_in[8];
    const float* b_gen2 = (const float*)d_in[9];
    const float* W_load1 = (const float*)d_in[10];
    const float* b_load1 = (const float*)d_in[11];
    const float* W_load2 = (const float*)d_in[12];
    const float* b_load2 = (const float*)d_in[13];
    const float* W_or1 = (const float*)d_in[14];
    const float* b_or1 = (const float*)d_in[15];
    const float* W_or2 = (const float*)d_in[16];
    const float* b_or2 = (const float*)d_in[17];
    const float* W_ex1 = (const float*)d_in[18];
    const float* b_ex1 = (const float*)d_in[19];
    const float* W_ex2 = (const float*)d_in[20];
    const float* b_ex2 = (const float*)d_in[21];
    const float* Wl_h = (const float*)d_in[22];
    const float* Wr_h = (const float*)d_in[23];
    const float* b_h = (const float*)d_in[24];
    const float* Wl_last = (const float*)d_in[25];
    const float* Wr_last = (const float*)d_in[26];
    const float* b_last = (const float*)d_in[27];

    int n_gen = in_sizes[0] / 3;
    int n_load = in_sizes[1] / 3;
    int n_or = in_sizes[2] / 6;
    int n_ex = in_sizes[3] / 6;
    int E_ = in_sizes[4] / 2;
    int N_ = in_sizes[5];
    const int* srcv = edge;        // row 0
    const int* dstv = edge + E_;   // row 1

    char* ws = (char*)d_ws;
    size_t off = 0;
    auto alloc = [&](size_t bytes) -> void* {
        void* p = ws + off;
        off = (off + bytes + 255) & ~(size_t)255;
        return p;
    };
    float* enc = (float*)alloc((size_t)N_ * HD * 4);
    float* hA = (float*)alloc((size_t)N_ * HD * 4);
    float* hB = (float*)alloc((size_t)N_ * HD * 4);
    int* counts = (int*)alloc((size_t)N_ * 4);
    int* row_ptr = (int*)alloc((size_t)(N_ + 1) * 4);
    int* pos = (int*)alloc((size_t)N_ * 4);
    int* bsum = (int*)alloc(256 * 4);
    int* csr_col = (int*)alloc((size_t)E_ * 4);
    (void)ws_size;

    zero_i32<<<256, 256, 0, stream>>>(counts, N_);

    encode_k<3><<<(n_gen + 3) / 4, 256, 0, stream>>>(x_gen, W_gen1, b_gen1, W_gen2, b_gen2,
                                                     enc, n_gen);
    encode_k<3><<<(n_load + 3) / 4, 256, 0, stream>>>(x_load, W_load1, b_load1, W_load2, b_load2,
                                                      enc + (size_t)n_gen * HD, n_load);
    encode_k<6><<<(n_or + 3) / 4, 256, 0, stream>>>(x_or, W_or1, b_or1, W_or2, b_or2,
                                                    enc + (size_t)(n_gen + n_load) * HD, n_or);
    encode_k<6><<<(n_ex + 3) / 4, 256, 0, stream>>>(x_ex, W_ex1, b_ex1, W_ex2, b_ex2,
                                                    enc + (size_t)(n_gen + n_load + n_or) * HD, n_ex);

    gather_k<<<2048, 256, 0, stream>>>(enc, ptv, hA, N_);

    hist_k<<<2048, 256, 0, stream>>>(dstv, counts, E_);
    int nb = (N_ + CHUNK - 1) / CHUNK;
    scan1<<<nb, 256, 0, stream>>>(counts, bsum, N_);
    scan2<<<1, 64, 0, stream>>>(bsum, nb, row_ptr, N_);
    scan3<<<nb, 256, 0, stream>>>(counts, bsum, row_ptr, pos, N_);
    scatter_k<<<2048, 256, 0, stream>>>(srcv, dstv, pos, csr_col, E_);

    float* cur = hA;
    float* nxt = hB;
    for (int l = 0; l < 7; ++l) {
        sage_hidden<<<2048, 256, 0, stream>>>(cur, nxt, row_ptr, csr_col,
                                              Wl_h + (size_t)l * HD * HD,
                                              Wr_h + (size_t)l * HD * HD,
                                              b_h + (size_t)l * HD, N_);
        float* t = cur;
        cur = nxt;
        nxt = t;
    }
    sage_last<<<2048, 256, 0, stream>>>(cur, (float*)d_out, row_ptr, csr_col,
                                        Wl_last, Wr_last, b_last, N_);
}

// Round 2
// 2110.588 us; speedup vs baseline: 1.4359x; 1.4359x over previous
//
#include <hip/hip_runtime.h>
#include <math.h>

#define HD 64
#define NEGS 0.1f
#define CHUNK 2048

__device__ __forceinline__ float leaky(float v) { return v > 0.f ? v : NEGS * v; }

__global__ void zero_i32(int* __restrict__ p, int n) {
    int i = blockIdx.x * blockDim.x + threadIdx.x;
    int stride = gridDim.x * blockDim.x;
    for (; i < n; i += stride) p[i] = 0;
}

// One wave per node; lane = output feature. 2-layer MLP encoder.
template <int IN>
__global__ void encode_k(const float* __restrict__ x,
                         const float* __restrict__ W1, const float* __restrict__ b1,
                         const float* __restrict__ W2, const float* __restrict__ b2,
                         float* __restrict__ out, int n) {
    __shared__ float sW2[HD * HD];
    for (int idx = threadIdx.x; idx < HD * HD; idx += blockDim.x) sW2[idx] = W2[idx];
    __syncthreads();
    int wave = threadIdx.x >> 6, lane = threadIdx.x & 63;
    int i = blockIdx.x * 4 + wave;
    if (i >= n) return;
    float h1 = b1[lane];
#pragma unroll
    for (int d = 0; d < IN; ++d) h1 += x[i * IN + d] * W1[d * HD + lane];
    h1 = leaky(h1);
    float h2 = b2[lane];
#pragma unroll
    for (int k = 0; k < HD; ++k) {
        float hk = __shfl(h1, k);
        h2 += hk * sW2[k * HD + lane];
    }
    out[i * HD + lane] = leaky(h2);
}

__global__ void gather_k(const float* __restrict__ enc, const int* __restrict__ ptv,
                         float* __restrict__ out, int n) {
    int idx = blockIdx.x * blockDim.x + threadIdx.x;
    int stride = gridDim.x * blockDim.x;
    int total = n * HD;
    for (; idx < total; idx += stride) {
        int i = idx >> 6, j = idx & 63;
        out[idx] = enc[ptv[i] * HD + j];
    }
}

__global__ void hist_k(const int* __restrict__ dst, int* __restrict__ counts, int E_) {
    for (int e = blockIdx.x * blockDim.x + threadIdx.x; e < E_; e += gridDim.x * blockDim.x)
        atomicAdd(&counts[dst[e]], 1);
}

__global__ void scan1(const int* __restrict__ counts, int* __restrict__ bsum, int n) {
    __shared__ int s[256];
    int b = blockIdx.x, t = threadIdx.x;
    int base = b * CHUNK + t * 8;
    int sum = 0;
#pragma unroll
    for (int u = 0; u < 8; ++u) {
        int i = base + u;
        if (i < n) sum += counts[i];
    }
    s[t] = sum;
    __syncthreads();
    for (int off = 128; off > 0; off >>= 1) {
        if (t < off) s[t] += s[t + off];
        __syncthreads();
    }
    if (t == 0) bsum[b] = s[0];
}

__global__ void scan2(int* __restrict__ bsum, int nb, int* __restrict__ row_ptr, int n) {
    if (threadIdx.x == 0 && blockIdx.x == 0) {
        int run = 0;
        for (int b = 0; b < nb; ++b) {
            int v = bsum[b];
            bsum[b] = run;
            run += v;
        }
        row_ptr[n] = run;
    }
}

__global__ void scan3(const int* __restrict__ counts, const int* __restrict__ bsum,
                      int* __restrict__ row_ptr, int* __restrict__ pos, int n) {
    __shared__ int s[256];
    int b = blockIdx.x, t = threadIdx.x;
    int base = b * CHUNK + t * 8;
    int c[8];
    int sum = 0;
#pragma unroll
    for (int u = 0; u < 8; ++u) {
        int i = base + u;
        c[u] = (i < n) ? counts[i] : 0;
        sum += c[u];
    }
    s[t] = sum;
    __syncthreads();
    for (int off = 1; off < 256; off <<= 1) {
        int v = (t >= off) ? s[t - off] : 0;
        __syncthreads();
        s[t] += v;
        __syncthreads();
    }
    int run = bsum[b] + s[t] - sum;  // exclusive prefix for this thread
#pragma unroll
    for (int u = 0; u < 8; ++u) {
        int i = base + u;
        if (i < n) {
            row_ptr[i] = run;
            pos[i] = run;
            run += c[u];
        }
    }
}

__global__ void scatter_k(const int* __restrict__ src, const int* __restrict__ dst,
                          int* __restrict__ pos, int* __restrict__ col, int E_) {
    for (int e = blockIdx.x * blockDim.x + threadIdx.x; e < E_; e += gridDim.x * blockDim.x) {
        int d = dst[e];
        int p = atomicAdd(&pos[d], 1);
        col[p] = src[e];
    }
}

// One wave per node. 4 neighbor streams (16 lanes each), float4 per lane,
// 2-deep unroll -> up to 4 outstanding 1KB gathers per wave. No LDS,
// low VGPR -> full occupancy.
__global__ void __launch_bounds__(256) agg_k(const float* __restrict__ hin,
                                             float* __restrict__ agg,
                                             const int* __restrict__ row_ptr,
                                             const int* __restrict__ col, int n) {
    int wid = threadIdx.x >> 6, lane = threadIdx.x & 63;
    int g = lane >> 4, s = lane & 15;
    int wpb = blockDim.x >> 6;
    int stride = gridDim.x * wpb;
    for (int i = blockIdx.x * wpb + wid; i < n; i += stride) {
        int beg = row_ptr[i], end = row_ptr[i + 1];
        float4 a0 = make_float4(0.f, 0.f, 0.f, 0.f);
        float4 a1 = make_float4(0.f, 0.f, 0.f, 0.f);
        int k = beg + g;
        for (; k + 4 < end; k += 8) {
            int c0 = col[k];
            int c1 = col[k + 4];
            float4 v0 = ((const float4*)(hin + (size_t)c0 * HD))[s];
            float4 v1 = ((const float4*)(hin + (size_t)c1 * HD))[s];
            a0.x += v0.x; a0.y += v0.y; a0.z += v0.z; a0.w += v0.w;
            a1.x += v1.x; a1.y += v1.y; a1.z += v1.z; a1.w += v1.w;
        }
        if (k < end) {
            int c0 = col[k];
            float4 v0 = ((const float4*)(hin + (size_t)c0 * HD))[s];
            a0.x += v0.x; a0.y += v0.y; a0.z += v0.z; a0.w += v0.w;
        }
        a0.x += a1.x; a0.y += a1.y; a0.z += a1.z; a0.w += a1.w;
        a0.x += __shfl_xor(a0.x, 16);
        a0.y += __shfl_xor(a0.y, 16);
        a0.z += __shfl_xor(a0.z, 16);
        a0.w += __shfl_xor(a0.w, 16);
        a0.x += __shfl_xor(a0.x, 32);
        a0.y += __shfl_xor(a0.y, 32);
        a0.z += __shfl_xor(a0.z, 32);
        a0.w += __shfl_xor(a0.w, 32);
        if (g == 0) ((float4*)(agg + (size_t)i * HD))[s] = a0;
    }
}

// hout = leaky(agg @ Wl + h @ Wr + b). Lane = output feature j; each lane
// holds columns Wl[:,j], Wr[:,j] in 128 VGPRs (loaded once). x rows are
// broadcast via uniform-address float4 loads. No LDS.
__global__ void __launch_bounds__(256) sage_gemm(const float* __restrict__ agg,
                                                 const float* __restrict__ h,
                                                 float* __restrict__ hout,
                                                 const float* __restrict__ Wl,
                                                 const float* __restrict__ Wr,
                                                 const float* __restrict__ bias, int n) {
    int wid = threadIdx.x >> 6, lane = threadIdx.x & 63;
    float wl[HD], wr[HD];
#pragma unroll
    for (int k = 0; k < HD; ++k) {
        wl[k] = Wl[k * HD + lane];
        wr[k] = Wr[k * HD + lane];
    }
    float bj = bias[lane];
    int wpb = blockDim.x >> 6;
    int stride = gridDim.x * wpb;
    for (int i = blockIdx.x * wpb + wid; i < n; i += stride) {
        const float4* ar = (const float4*)(agg + (size_t)i * HD);
        const float4* hr = (const float4*)(h + (size_t)i * HD);
        float o = bj;
#pragma unroll
        for (int c = 0; c < HD / 4; ++c) {
            float4 av = ar[c];
            float4 hv = hr[c];
            o += av.x * wl[4 * c] + av.y * wl[4 * c + 1] + av.z * wl[4 * c + 2] + av.w * wl[4 * c + 3];
            o += hv.x * wr[4 * c] + hv.y * wr[4 * c + 1] + hv.z * wr[4 * c + 2] + hv.w * wr[4 * c + 3];
        }
        hout[(size_t)i * HD + lane] = leaky(o);
    }
}

__global__ void sage_last_k(const float* __restrict__ agg, const float* __restrict__ h,
                            float* __restrict__ out,
                            const float* __restrict__ Wl, const float* __restrict__ Wr,
                            const float* __restrict__ bias, int n) {
    int wid = threadIdx.x >> 6, lane = threadIdx.x & 63;
    float wl = Wl[lane], wr = Wr[lane];
    float b0 = bias[0];
    int wpb = blockDim.x >> 6;
    int stride = gridDim.x * wpb;
    for (int i = blockIdx.x * wpb + wid; i < n; i += stride) {
        float v = agg[(size_t)i * HD + lane] * wl + h[(size_t)i * HD + lane] * wr;
#pragma unroll
        for (int off = 32; off > 0; off >>= 1) v += __shfl_xor(v, off);
        if (lane == 0) out[i] = 1.f / (1.f + expf(-(v + b0)));
    }
}

extern "C" void kernel_launch(void* const* d_in, const int* in_sizes, int n_in,
                              void* d_out, int out_size, void* d_ws, size_t ws_size,
                              hipStream_t stream) {
    const float* x_gen = (const float*)d_in[0];
    const float* x_load = (const float*)d_in[1];
    const float* x_or = (const float*)d_in[2];
    const float* x_ex = (const float*)d_in[3];
    const int* edge = (const int*)d_in[4];
    const int* ptv = (const int*)d_in[5];
    const float* W_gen1 = (const float*)d_in[6];
    const float* b_gen1 = (const float*)d_in[7];
    const float* W_gen2 = (const float*)d_in[8];
    const float* b_gen2 = (const float*)d_in[9];
    const float* W_load1 = (const float*)d_in[10];
    const float* b_load1 = (const float*)d_in[11];
    const float* W_load2 = (const float*)d_in[12];
    const float* b_load2 = (const float*)d_in[13];
    const float* W_or1 = (const float*)d_in[14];
    const float* b_or1 = (const float*)d_in[15];
    const float* W_or2 = (const float*)d_in[16];
    const float* b_or2 = (const float*)d_in[17];
    const float* W_ex1 = (const float*)d_in[18];
    const float* b_ex1 = (const float*)d_in[19];
    const float* W_ex2 = (const float*)d_in[20];
    const float* b_ex2 = (const float*)d_in[21];
    const float* Wl_h = (const float*)d_in[22];
    const float* Wr_h = (const float*)d_in[23];
    const float* b_h = (const float*)d_in[24];
    const float* Wl_last = (const float*)d_in[25];
    const float* Wr_last = (const float*)d_in[26];
    const float* b_last = (const float*)d_in[27];

    int n_gen = in_sizes[0] / 3;
    int n_load = in_sizes[1] / 3;
    int n_or = in_sizes[2] / 6;
    int n_ex = in_sizes[3] / 6;
    int E_ = in_sizes[4] / 2;
    int N_ = in_sizes[5];
    const int* srcv = edge;        // row 0
    const int* dstv = edge + E_;   // row 1

    char* ws = (char*)d_ws;
    size_t off = 0;
    auto alloc = [&](size_t bytes) -> void* {
        void* p = ws + off;
        off = (off + bytes + 255) & ~(size_t)255;
        return p;
    };
    float* enc = (float*)alloc((size_t)N_ * HD * 4);  // reused as agg after gather
    float* hA = (float*)alloc((size_t)N_ * HD * 4);
    float* hB = (float*)alloc((size_t)N_ * HD * 4);
    int* counts = (int*)alloc((size_t)N_ * 4);
    int* row_ptr = (int*)alloc((size_t)(N_ + 1) * 4);
    int* pos = (int*)alloc((size_t)N_ * 4);
    int* bsum = (int*)alloc(256 * 4);
    int* csr_col = (int*)alloc((size_t)E_ * 4);
    float* agg = enc;  // alias: enc is dead after gather_k
    (void)ws_size;

    zero_i32<<<256, 256, 0, stream>>>(counts, N_);

    encode_k<3><<<(n_gen + 3) / 4, 256, 0, stream>>>(x_gen, W_gen1, b_gen1, W_gen2, b_gen2,
                                                     enc, n_gen);
    encode_k<3><<<(n_load + 3) / 4, 256, 0, stream>>>(x_load, W_load1, b_load1, W_load2, b_load2,
                                                      enc + (size_t)n_gen * HD, n_load);
    encode_k<6><<<(n_or + 3) / 4, 256, 0, stream>>>(x_or, W_or1, b_or1, W_or2, b_or2,
                                                    enc + (size_t)(n_gen + n_load) * HD, n_or);
    encode_k<6><<<(n_ex + 3) / 4, 256, 0, stream>>>(x_ex, W_ex1, b_ex1, W_ex2, b_ex2,
                                                    enc + (size_t)(n_gen + n_load + n_or) * HD, n_ex);

    gather_k<<<2048, 256, 0, stream>>>(enc, ptv, hA, N_);

    hist_k<<<2048, 256, 0, stream>>>(dstv, counts, E_);
    int nb = (N_ + CHUNK - 1) / CHUNK;
    scan1<<<nb, 256, 0, stream>>>(counts, bsum, N_);
    scan2<<<1, 64, 0, stream>>>(bsum, nb, row_ptr, N_);
    scan3<<<nb, 256, 0, stream>>>(counts, bsum, row_ptr, pos, N_);
    scatter_k<<<2048, 256, 0, stream>>>(srcv, dstv, pos, csr_col, E_);

    float* cur = hA;
    float* nxt = hB;
    for (int l = 0; l < 7; ++l) {
        agg_k<<<4096, 256, 0, stream>>>(cur, agg, row_ptr, csr_col, N_);
        sage_gemm<<<1536, 256, 0, stream>>>(agg, cur, nxt,
                                            Wl_h + (size_t)l * HD * HD,
                                            Wr_h + (size_t)l * HD * HD,
                                            b_h + (size_t)l * HD, N_);
        float* t = cur;
        cur = nxt;
        nxt = t;
    }
    agg_k<<<4096, 256, 0, stream>>>(cur, agg, row_ptr, csr_col, N_);
    sage_last_k<<<1024, 256, 0, stream>>>(agg, cur, (float*)d_out,
                                          Wl_last, Wr_last, b_last, N_);
}

// Round 3
// 1102.842 us; speedup vs baseline: 2.7479x; 1.9138x over previous
//
#include <hip/hip_runtime.h>
#include <math.h>

#define HD 64
#define NEGS 0.1f
#define CHUNK 2048

__device__ __forceinline__ float leaky(float v) { return v > 0.f ? v : NEGS * v; }

__global__ void zero_i32(int* __restrict__ p, int n) {
    int i = blockIdx.x * blockDim.x + threadIdx.x;
    int stride = gridDim.x * blockDim.x;
    for (; i < n; i += stride) p[i] = 0;
}

// One wave per node; lane = output feature. 2-layer MLP encoder.
template <int IN>
__global__ void encode_k(const float* __restrict__ x,
                         const float* __restrict__ W1, const float* __restrict__ b1,
                         const float* __restrict__ W2, const float* __restrict__ b2,
                         float* __restrict__ out, int n) {
    __shared__ float sW2[HD * HD];
    for (int idx = threadIdx.x; idx < HD * HD; idx += blockDim.x) sW2[idx] = W2[idx];
    __syncthreads();
    int wave = threadIdx.x >> 6, lane = threadIdx.x & 63;
    int i = blockIdx.x * 4 + wave;
    if (i >= n) return;
    float h1 = b1[lane];
#pragma unroll
    for (int d = 0; d < IN; ++d) h1 += x[i * IN + d] * W1[d * HD + lane];
    h1 = leaky(h1);
    float h2 = b2[lane];
#pragma unroll
    for (int k = 0; k < HD; ++k) {
        float hk = __shfl(h1, k);
        h2 += hk * sW2[k * HD + lane];
    }
    out[i * HD + lane] = leaky(h2);
}

__global__ void gather_k(const float* __restrict__ enc, const int* __restrict__ ptv,
                         float* __restrict__ out, int n) {
    int idx = blockIdx.x * blockDim.x + threadIdx.x;
    int stride = gridDim.x * blockDim.x;
    int total = n * HD;
    for (; idx < total; idx += stride) {
        int i = idx >> 6, j = idx & 63;
        out[idx] = enc[ptv[i] * HD + j];
    }
}

__global__ void hist_k(const int* __restrict__ dst, int* __restrict__ counts, int E_) {
    for (int e = blockIdx.x * blockDim.x + threadIdx.x; e < E_; e += gridDim.x * blockDim.x)
        atomicAdd(&counts[dst[e]], 1);
}

__global__ void scan1(const int* __restrict__ counts, int* __restrict__ bsum, int n) {
    __shared__ int s[256];
    int b = blockIdx.x, t = threadIdx.x;
    int base = b * CHUNK + t * 8;
    int sum = 0;
#pragma unroll
    for (int u = 0; u < 8; ++u) {
        int i = base + u;
        if (i < n) sum += counts[i];
    }
    s[t] = sum;
    __syncthreads();
    for (int off = 128; off > 0; off >>= 1) {
        if (t < off) s[t] += s[t + off];
        __syncthreads();
    }
    if (t == 0) bsum[b] = s[0];
}

__global__ void scan2(int* __restrict__ bsum, int nb, int* __restrict__ row_ptr, int n) {
    if (threadIdx.x == 0 && blockIdx.x == 0) {
        int run = 0;
        for (int b = 0; b < nb; ++b) {
            int v = bsum[b];
            bsum[b] = run;
            run += v;
        }
        row_ptr[n] = run;
    }
}

__global__ void scan3(const int* __restrict__ counts, const int* __restrict__ bsum,
                      int* __restrict__ row_ptr, int* __restrict__ pos, int n) {
    __shared__ int s[256];
    int b = blockIdx.x, t = threadIdx.x;
    int base = b * CHUNK + t * 8;
    int c[8];
    int sum = 0;
#pragma unroll
    for (int u = 0; u < 8; ++u) {
        int i = base + u;
        c[u] = (i < n) ? counts[i] : 0;
        sum += c[u];
    }
    s[t] = sum;
    __syncthreads();
    for (int off = 1; off < 256; off <<= 1) {
        int v = (t >= off) ? s[t - off] : 0;
        __syncthreads();
        s[t] += v;
        __syncthreads();
    }
    int run = bsum[b] + s[t] - sum;  // exclusive prefix for this thread
#pragma unroll
    for (int u = 0; u < 8; ++u) {
        int i = base + u;
        if (i < n) {
            row_ptr[i] = run;
            pos[i] = run;
            run += c[u];
        }
    }
}

__global__ void scatter_k(const int* __restrict__ src, const int* __restrict__ dst,
                          int* __restrict__ pos, int* __restrict__ col, int E_) {
    for (int e = blockIdx.x * blockDim.x + threadIdx.x; e < E_; e += gridDim.x * blockDim.x) {
        int d = dst[e];
        int p = atomicAdd(&pos[d], 1);
        col[p] = src[e];
    }
}

// One wave per node. 4 neighbor streams (16 lanes each), float4 per lane,
// 4-deep unroll -> up to 16 outstanding 256B row-gathers per wave. No LDS.
__global__ void __launch_bounds__(256) agg_k(const float* __restrict__ hin,
                                             float* __restrict__ agg,
                                             const int* __restrict__ row_ptr,
                                             const int* __restrict__ col, int n) {
    int wid = threadIdx.x >> 6, lane = threadIdx.x & 63;
    int g = lane >> 4, s = lane & 15;
    int wpb = blockDim.x >> 6;
    int stride = gridDim.x * wpb;
    for (int i = blockIdx.x * wpb + wid; i < n; i += stride) {
        int beg = row_ptr[i], end = row_ptr[i + 1];
        float4 a0 = make_float4(0.f, 0.f, 0.f, 0.f);
        float4 a1 = make_float4(0.f, 0.f, 0.f, 0.f);
        float4 a2 = make_float4(0.f, 0.f, 0.f, 0.f);
        float4 a3 = make_float4(0.f, 0.f, 0.f, 0.f);
        int k = beg + g;
        for (; k + 12 < end; k += 16) {
            int c0 = col[k];
            int c1 = col[k + 4];
            int c2 = col[k + 8];
            int c3 = col[k + 12];
            float4 v0 = ((const float4*)(hin + (size_t)c0 * HD))[s];
            float4 v1 = ((const float4*)(hin + (size_t)c1 * HD))[s];
            float4 v2 = ((const float4*)(hin + (size_t)c2 * HD))[s];
            float4 v3 = ((const float4*)(hin + (size_t)c3 * HD))[s];
            a0.x += v0.x; a0.y += v0.y; a0.z += v0.z; a0.w += v0.w;
            a1.x += v1.x; a1.y += v1.y; a1.z += v1.z; a1.w += v1.w;
            a2.x += v2.x; a2.y += v2.y; a2.z += v2.z; a2.w += v2.w;
            a3.x += v3.x; a3.y += v3.y; a3.z += v3.z; a3.w += v3.w;
        }
        for (; k < end; k += 4) {
            int c0 = col[k];
            float4 v0 = ((const float4*)(hin + (size_t)c0 * HD))[s];
            a0.x += v0.x; a0.y += v0.y; a0.z += v0.z; a0.w += v0.w;
        }
        a0.x += a1.x + a2.x + a3.x;
        a0.y += a1.y + a2.y + a3.y;
        a0.z += a1.z + a2.z + a3.z;
        a0.w += a1.w + a2.w + a3.w;
        a0.x += __shfl_xor(a0.x, 16);
        a0.y += __shfl_xor(a0.y, 16);
        a0.z += __shfl_xor(a0.z, 16);
        a0.w += __shfl_xor(a0.w, 16);
        a0.x += __shfl_xor(a0.x, 32);
        a0.y += __shfl_xor(a0.y, 32);
        a0.z += __shfl_xor(a0.z, 32);
        a0.w += __shfl_xor(a0.w, 32);
        if (g == 0) ((float4*)(agg + (size_t)i * HD))[s] = a0;
    }
}

// hout = leaky([agg|h] @ [[Wl],[Wr]] + b). LDS-tiled reg-blocked fp32 GEMM:
// 64-node tile, 256 threads, 4x4 micro-tile per thread. K = 128.
__global__ void __launch_bounds__(256) sage_gemm_tile(const float* __restrict__ agg,
                                                      const float* __restrict__ h,
                                                      float* __restrict__ hout,
                                                      const float* __restrict__ Wl,
                                                      const float* __restrict__ Wr,
                                                      const float* __restrict__ bias, int n) {
    __shared__ float Ws[128][64];   // rows 0..63 = Wl, 64..127 = Wr
    __shared__ float Xs[64][132];   // cols 0..63 = agg row, 64..127 = h row (pad 4)
    int tid = threadIdx.x;
    for (int idx = tid; idx < 64 * 64; idx += 256) {
        int k = idx >> 6, j = idx & 63;
        Ws[k][j] = Wl[idx];
        Ws[64 + k][j] = Wr[idx];
    }
    int tcol = tid & 15, trow = tid >> 4;
    int j0 = tcol * 4;
    float b0 = bias[j0], b1 = bias[j0 + 1], b2 = bias[j0 + 2], b3 = bias[j0 + 3];
    int ntiles = (n + 63) >> 6;
    for (int t = blockIdx.x; t < ntiles; t += gridDim.x) {
        int base = t << 6;
        __syncthreads();  // Xs safe to overwrite (also orders Ws staging on iter 0)
#pragma unroll
        for (int u = 0; u < 8; ++u) {
            int idx = tid + u * 256;   // row = idx>>5, float4-col = idx&31
            int row = idx >> 5, c4 = idx & 31;
            int grow = base + row;
            float4 v = make_float4(0.f, 0.f, 0.f, 0.f);
            if (grow < n) {
                v = (c4 < 16) ? ((const float4*)(agg + (size_t)grow * HD))[c4]
                              : ((const float4*)(h + (size_t)grow * HD))[c4 - 16];
            }
            *(float4*)&Xs[row][c4 * 4] = v;
        }
        __syncthreads();
        float acc[4][4];
#pragma unroll
        for (int r = 0; r < 4; ++r)
#pragma unroll
            for (int c = 0; c < 4; ++c) acc[r][c] = 0.f;
#pragma unroll 4
        for (int k4 = 0; k4 < 32; ++k4) {
            int k = k4 * 4;
            float4 x0 = *(const float4*)&Xs[trow][k];
            float4 x1 = *(const float4*)&Xs[trow + 16][k];
            float4 x2 = *(const float4*)&Xs[trow + 32][k];
            float4 x3 = *(const float4*)&Xs[trow + 48][k];
            float4 w0 = *(const float4*)&Ws[k][j0];
            float4 w1 = *(const float4*)&Ws[k + 1][j0];
            float4 w2 = *(const float4*)&Ws[k + 2][j0];
            float4 w3 = *(const float4*)&Ws[k + 3][j0];
            float4 xr[4] = {x0, x1, x2, x3};
#pragma unroll
            for (int r = 0; r < 4; ++r) {
                acc[r][0] += xr[r].x * w0.x + xr[r].y * w1.x + xr[r].z * w2.x + xr[r].w * w3.x;
                acc[r][1] += xr[r].x * w0.y + xr[r].y * w1.y + xr[r].z * w2.y + xr[r].w * w3.y;
                acc[r][2] += xr[r].x * w0.z + xr[r].y * w1.z + xr[r].z * w2.z + xr[r].w * w3.z;
                acc[r][3] += xr[r].x * w0.w + xr[r].y * w1.w + xr[r].z * w2.w + xr[r].w * w3.w;
            }
        }
#pragma unroll
        for (int r = 0; r < 4; ++r) {
            int grow = base + trow + 16 * r;
            if (grow < n) {
                float4 o;
                o.x = leaky(acc[r][0] + b0);
                o.y = leaky(acc[r][1] + b1);
                o.z = leaky(acc[r][2] + b2);
                o.w = leaky(acc[r][3] + b3);
                *(float4*)(hout + (size_t)grow * HD + j0) = o;
            }
        }
    }
}

__global__ void sage_last_k(const float* __restrict__ agg, const float* __restrict__ h,
                            float* __restrict__ out,
                            const float* __restrict__ Wl, const float* __restrict__ Wr,
                            const float* __restrict__ bias, int n) {
    int wid = threadIdx.x >> 6, lane = threadIdx.x & 63;
    float wl = Wl[lane], wr = Wr[lane];
    float b0 = bias[0];
    int wpb = blockDim.x >> 6;
    int stride = gridDim.x * wpb;
    for (int i = blockIdx.x * wpb + wid; i < n; i += stride) {
        float v = agg[(size_t)i * HD + lane] * wl + h[(size_t)i * HD + lane] * wr;
#pragma unroll
        for (int off = 32; off > 0; off >>= 1) v += __shfl_xor(v, off);
        if (lane == 0) out[i] = 1.f / (1.f + expf(-(v + b0)));
    }
}

extern "C" void kernel_launch(void* const* d_in, const int* in_sizes, int n_in,
                              void* d_out, int out_size, void* d_ws, size_t ws_size,
                              hipStream_t stream) {
    const float* x_gen = (const float*)d_in[0];
    const float* x_load = (const float*)d_in[1];
    const float* x_or = (const float*)d_in[2];
    const float* x_ex = (const float*)d_in[3];
    const int* edge = (const int*)d_in[4];
    const int* ptv = (const int*)d_in[5];
    const float* W_gen1 = (const float*)d_in[6];
    const float* b_gen1 = (const float*)d_in[7];
    const float* W_gen2 = (const float*)d_in[8];
    const float* b_gen2 = (const float*)d_in[9];
    const float* W_load1 = (const float*)d_in[10];
    const float* b_load1 = (const float*)d_in[11];
    const float* W_load2 = (const float*)d_in[12];
    const float* b_load2 = (const float*)d_in[13];
    const float* W_or1 = (const float*)d_in[14];
    const float* b_or1 = (const float*)d_in[15];
    const float* W_or2 = (const float*)d_in[16];
    const float* b_or2 = (const float*)d_in[17];
    const float* W_ex1 = (const float*)d_in[18];
    const float* b_ex1 = (const float*)d_in[19];
    const float* W_ex2 = (const float*)d_in[20];
    const float* b_ex2 = (const float*)d_in[21];
    const float* Wl_h = (const float*)d_in[22];
    const float* Wr_h = (const float*)d_in[23];
    const float* b_h = (const float*)d_in[24];
    const float* Wl_last = (const float*)d_in[25];
    const float* Wr_last = (const float*)d_in[26];
    const float* b_last = (const float*)d_in[27];

    int n_gen = in_sizes[0] / 3;
    int n_load = in_sizes[1] / 3;
    int n_or = in_sizes[2] / 6;
    int n_ex = in_sizes[3] / 6;
    int E_ = in_sizes[4] / 2;
    int N_ = in_sizes[5];
    const int* srcv = edge;        // row 0
    const int* dstv = edge + E_;   // row 1

    char* ws = (char*)d_ws;
    size_t off = 0;
    auto alloc = [&](size_t bytes) -> void* {
        void* p = ws + off;
        off = (off + bytes + 255) & ~(size_t)255;
        return p;
    };
    float* enc = (float*)alloc((size_t)N_ * HD * 4);  // reused as agg after gather
    float* hA = (float*)alloc((size_t)N_ * HD * 4);
    float* hB = (float*)alloc((size_t)N_ * HD * 4);
    int* counts = (int*)alloc((size_t)N_ * 4);
    int* row_ptr = (int*)alloc((size_t)(N_ + 1) * 4);
    int* pos = (int*)alloc((size_t)N_ * 4);
    int* bsum = (int*)alloc(256 * 4);
    int* csr_col = (int*)alloc((size_t)E_ * 4);
    float* agg = enc;  // alias: enc is dead after gather_k
    (void)ws_size;

    zero_i32<<<256, 256, 0, stream>>>(counts, N_);

    encode_k<3><<<(n_gen + 3) / 4, 256, 0, stream>>>(x_gen, W_gen1, b_gen1, W_gen2, b_gen2,
                                                     enc, n_gen);
    encode_k<3><<<(n_load + 3) / 4, 256, 0, stream>>>(x_load, W_load1, b_load1, W_load2, b_load2,
                                                      enc + (size_t)n_gen * HD, n_load);
    encode_k<6><<<(n_or + 3) / 4, 256, 0, stream>>>(x_or, W_or1, b_or1, W_or2, b_or2,
                                                    enc + (size_t)(n_gen + n_load) * HD, n_or);
    encode_k<6><<<(n_ex + 3) / 4, 256, 0, stream>>>(x_ex, W_ex1, b_ex1, W_ex2, b_ex2,
                                                    enc + (size_t)(n_gen + n_load + n_or) * HD, n_ex);

    gather_k<<<2048, 256, 0, stream>>>(enc, ptv, hA, N_);

    hist_k<<<2048, 256, 0, stream>>>(dstv, counts, E_);
    int nb = (N_ + CHUNK - 1) / CHUNK;
    scan1<<<nb, 256, 0, stream>>>(counts, bsum, N_);
    scan2<<<1, 64, 0, stream>>>(bsum, nb, row_ptr, N_);
    scan3<<<nb, 256, 0, stream>>>(counts, bsum, row_ptr, pos, N_);
    scatter_k<<<2048, 256, 0, stream>>>(srcv, dstv, pos, csr_col, E_);

    int ntiles = (N_ + 63) >> 6;
    float* cur = hA;
    float* nxt = hB;
    for (int l = 0; l < 7; ++l) {
        agg_k<<<4096, 256, 0, stream>>>(cur, agg, row_ptr, csr_col, N_);
        sage_gemm_tile<<<ntiles, 256, 0, stream>>>(agg, cur, nxt,
                                                   Wl_h + (size_t)l * HD * HD,
                                                   Wr_h + (size_t)l * HD * HD,
                                                   b_h + (size_t)l * HD, N_);
        float* t = cur;
        cur = nxt;
        nxt = t;
    }
    agg_k<<<4096, 256, 0, stream>>>(cur, agg, row_ptr, csr_col, N_);
    sage_last_k<<<1024, 256, 0, stream>>>(agg, cur, (float*)d_out,
                                          Wl_last, Wr_last, b_last, N_);
}

// Round 4
// 986.170 us; speedup vs baseline: 3.0730x; 1.1183x over previous
//
#include <hip/hip_runtime.h>
#include <math.h>

#define HD 64
#define NEGS 0.1f
#define CHUNK 2048

__device__ __forceinline__ float leaky(float v) { return v > 0.f ? v : NEGS * v; }

__global__ void zero_i32(int* __restrict__ p, int n) {
    int i = blockIdx.x * blockDim.x + threadIdx.x;
    int stride = gridDim.x * blockDim.x;
    for (; i < n; i += stride) p[i] = 0;
}

// One wave per node; lane = output feature. 2-layer MLP encoder.
template <int IN>
__global__ void encode_k(const float* __restrict__ x,
                         const float* __restrict__ W1, const float* __restrict__ b1,
                         const float* __restrict__ W2, const float* __restrict__ b2,
                         float* __restrict__ out, int n) {
    __shared__ float sW2[HD * HD];
    for (int idx = threadIdx.x; idx < HD * HD; idx += blockDim.x) sW2[idx] = W2[idx];
    __syncthreads();
    int wave = threadIdx.x >> 6, lane = threadIdx.x & 63;
    int i = blockIdx.x * 4 + wave;
    if (i >= n) return;
    float h1 = b1[lane];
#pragma unroll
    for (int d = 0; d < IN; ++d) h1 += x[i * IN + d] * W1[d * HD + lane];
    h1 = leaky(h1);
    float h2 = b2[lane];
#pragma unroll
    for (int k = 0; k < HD; ++k) {
        float hk = __shfl(h1, k);
        h2 += hk * sW2[k * HD + lane];
    }
    out[i * HD + lane] = leaky(h2);
}

__global__ void gather_k(const float* __restrict__ enc, const int* __restrict__ ptv,
                         float* __restrict__ out, int n) {
    int idx = blockIdx.x * blockDim.x + threadIdx.x;
    int stride = gridDim.x * blockDim.x;
    int total = n * HD;
    for (; idx < total; idx += stride) {
        int i = idx >> 6, j = idx & 63;
        out[idx] = enc[ptv[i] * HD + j];
    }
}

__global__ void hist_k(const int* __restrict__ dst, int* __restrict__ counts, int E_) {
    for (int e = blockIdx.x * blockDim.x + threadIdx.x; e < E_; e += gridDim.x * blockDim.x)
        atomicAdd(&counts[dst[e]], 1);
}

__global__ void scan1(const int* __restrict__ counts, int* __restrict__ bsum, int n) {
    __shared__ int s[256];
    int b = blockIdx.x, t = threadIdx.x;
    int base = b * CHUNK + t * 8;
    int sum = 0;
#pragma unroll
    for (int u = 0; u < 8; ++u) {
        int i = base + u;
        if (i < n) sum += counts[i];
    }
    s[t] = sum;
    __syncthreads();
    for (int off = 128; off > 0; off >>= 1) {
        if (t < off) s[t] += s[t + off];
        __syncthreads();
    }
    if (t == 0) bsum[b] = s[0];
}

__global__ void scan2(int* __restrict__ bsum, int nb, int* __restrict__ row_ptr, int n) {
    if (threadIdx.x == 0 && blockIdx.x == 0) {
        int run = 0;
        for (int b = 0; b < nb; ++b) {
            int v = bsum[b];
            bsum[b] = run;
            run += v;
        }
        row_ptr[n] = run;
    }
}

__global__ void scan3(const int* __restrict__ counts, const int* __restrict__ bsum,
                      int* __restrict__ row_ptr, int* __restrict__ pos, int n) {
    __shared__ int s[256];
    int b = blockIdx.x, t = threadIdx.x;
    int base = b * CHUNK + t * 8;
    int c[8];
    int sum = 0;
#pragma unroll
    for (int u = 0; u < 8; ++u) {
        int i = base + u;
        c[u] = (i < n) ? counts[i] : 0;
        sum += c[u];
    }
    s[t] = sum;
    __syncthreads();
    for (int off = 1; off < 256; off <<= 1) {
        int v = (t >= off) ? s[t - off] : 0;
        __syncthreads();
        s[t] += v;
        __syncthreads();
    }
    int run = bsum[b] + s[t] - sum;  // exclusive prefix for this thread
#pragma unroll
    for (int u = 0; u < 8; ++u) {
        int i = base + u;
        if (i < n) {
            row_ptr[i] = run;
            pos[i] = run;
            run += c[u];
        }
    }
}

__global__ void scatter_k(const int* __restrict__ src, const int* __restrict__ dst,
                          int* __restrict__ pos, int* __restrict__ col, int E_) {
    for (int e = blockIdx.x * blockDim.x + threadIdx.x; e < E_; e += gridDim.x * blockDim.x) {
        int d = dst[e];
        int p = atomicAdd(&pos[d], 1);
        col[p] = src[e];
    }
}

// One wave per node. Neighbor indices for the whole node are loaded with ONE
// coalesced 64-lane load, then shfl-broadcast -> row gathers issue back-to-back
// with no address-load dependency. 4 groups x 16 lanes x float4, 2 streams.
__global__ void __launch_bounds__(256) agg_k(const float* __restrict__ hin,
                                             float* __restrict__ agg,
                                             const int* __restrict__ row_ptr,
                                             const int* __restrict__ col, int n) {
    int wid = threadIdx.x >> 6, lane = threadIdx.x & 63;
    int g = lane >> 4, s = lane & 15;
    int wpb = blockDim.x >> 6;
    int stride = gridDim.x * wpb;
    for (int i = blockIdx.x * wpb + wid; i < n; i += stride) {
        int beg = row_ptr[i], end = row_ptr[i + 1];
        int deg = end - beg;
        float4 a0 = make_float4(0.f, 0.f, 0.f, 0.f);
        float4 a1 = make_float4(0.f, 0.f, 0.f, 0.f);
        for (int base = 0; base < deg; base += 64) {
            int m = deg - base;
            if (m > 64) m = 64;
            int cidx = (lane < m) ? col[beg + base + lane] : 0;
            int k = g;
            for (; k + 4 < m; k += 8) {
                int c0 = __shfl(cidx, k);
                int c1 = __shfl(cidx, k + 4);
                float4 v0 = ((const float4*)(hin + (size_t)c0 * HD))[s];
                float4 v1 = ((const float4*)(hin + (size_t)c1 * HD))[s];
                a0.x += v0.x; a0.y += v0.y; a0.z += v0.z; a0.w += v0.w;
                a1.x += v1.x; a1.y += v1.y; a1.z += v1.z; a1.w += v1.w;
            }
            if (k < m) {
                int c0 = __shfl(cidx, k);
                float4 v0 = ((const float4*)(hin + (size_t)c0 * HD))[s];
                a0.x += v0.x; a0.y += v0.y; a0.z += v0.z; a0.w += v0.w;
            }
        }
        a0.x += a1.x; a0.y += a1.y; a0.z += a1.z; a0.w += a1.w;
        a0.x += __shfl_xor(a0.x, 16);
        a0.y += __shfl_xor(a0.y, 16);
        a0.z += __shfl_xor(a0.z, 16);
        a0.w += __shfl_xor(a0.w, 16);
        a0.x += __shfl_xor(a0.x, 32);
        a0.y += __shfl_xor(a0.y, 32);
        a0.z += __shfl_xor(a0.z, 32);
        a0.w += __shfl_xor(a0.w, 32);
        if (g == 0) ((float4*)(agg + (size_t)i * HD))[s] = a0;
    }
}

// hout = leaky([agg|h] @ [[Wl],[Wr]] + b). LDS-tiled reg-blocked fp32 GEMM:
// 64-node tile, 256 threads, 4x4 micro-tile. Weights staged ONCE per block,
// block loops over several tiles.
__global__ void __launch_bounds__(256) sage_gemm_tile(const float* __restrict__ agg,
                                                      const float* __restrict__ h,
                                                      float* __restrict__ hout,
                                                      const float* __restrict__ Wl,
                                                      const float* __restrict__ Wr,
                                                      const float* __restrict__ bias, int n) {
    __shared__ float Ws[128][64];   // rows 0..63 = Wl, 64..127 = Wr
    __shared__ float Xs[64][132];   // cols 0..63 = agg row, 64..127 = h row (pad 4)
    int tid = threadIdx.x;
    for (int idx = tid; idx < 64 * 64; idx += 256) {
        int k = idx >> 6, j = idx & 63;
        Ws[k][j] = Wl[idx];
        Ws[64 + k][j] = Wr[idx];
    }
    int tcol = tid & 15, trow = tid >> 4;
    int j0 = tcol * 4;
    float b0 = bias[j0], b1 = bias[j0 + 1], b2 = bias[j0 + 2], b3 = bias[j0 + 3];
    int ntiles = (n + 63) >> 6;
    for (int t = blockIdx.x; t < ntiles; t += gridDim.x) {
        int base = t << 6;
        __syncthreads();  // Xs safe to overwrite (also orders Ws staging on iter 0)
#pragma unroll
        for (int u = 0; u < 8; ++u) {
            int idx = tid + u * 256;   // row = idx>>5, float4-col = idx&31
            int row = idx >> 5, c4 = idx & 31;
            int grow = base + row;
            float4 v = make_float4(0.f, 0.f, 0.f, 0.f);
            if (grow < n) {
                v = (c4 < 16) ? ((const float4*)(agg + (size_t)grow * HD))[c4]
                              : ((const float4*)(h + (size_t)grow * HD))[c4 - 16];
            }
            *(float4*)&Xs[row][c4 * 4] = v;
        }
        __syncthreads();
        float acc[4][4];
#pragma unroll
        for (int r = 0; r < 4; ++r)
#pragma unroll
            for (int c = 0; c < 4; ++c) acc[r][c] = 0.f;
#pragma unroll 4
        for (int k4 = 0; k4 < 32; ++k4) {
            int k = k4 * 4;
            float4 x0 = *(const float4*)&Xs[trow][k];
            float4 x1 = *(const float4*)&Xs[trow + 16][k];
            float4 x2 = *(const float4*)&Xs[trow + 32][k];
            float4 x3 = *(const float4*)&Xs[trow + 48][k];
            float4 w0 = *(const float4*)&Ws[k][j0];
            float4 w1 = *(const float4*)&Ws[k + 1][j0];
            float4 w2 = *(const float4*)&Ws[k + 2][j0];
            float4 w3 = *(const float4*)&Ws[k + 3][j0];
            float4 xr[4] = {x0, x1, x2, x3};
#pragma unroll
            for (int r = 0; r < 4; ++r) {
                acc[r][0] += xr[r].x * w0.x + xr[r].y * w1.x + xr[r].z * w2.x + xr[r].w * w3.x;
                acc[r][1] += xr[r].x * w0.y + xr[r].y * w1.y + xr[r].z * w2.y + xr[r].w * w3.y;
                acc[r][2] += xr[r].x * w0.z + xr[r].y * w1.z + xr[r].z * w2.z + xr[r].w * w3.z;
                acc[r][3] += xr[r].x * w0.w + xr[r].y * w1.w + xr[r].z * w2.w + xr[r].w * w3.w;
            }
        }
#pragma unroll
        for (int r = 0; r < 4; ++r) {
            int grow = base + trow + 16 * r;
            if (grow < n) {
                float4 o;
                o.x = leaky(acc[r][0] + b0);
                o.y = leaky(acc[r][1] + b1);
                o.z = leaky(acc[r][2] + b2);
                o.w = leaky(acc[r][3] + b3);
                *(float4*)(hout + (size_t)grow * HD + j0) = o;
            }
        }
    }
}

// Last layer is rank-1: s_i = h_i . Wl, t_i = h_i . Wr computed first,
// then only SCALARS are aggregated over edges (4B/edge instead of 256B/edge).
__global__ void __launch_bounds__(256) dot_k(const float* __restrict__ h,
                                             const float* __restrict__ Wl,
                                             const float* __restrict__ Wr,
                                             float* __restrict__ sb, float* __restrict__ tb,
                                             int n) {
    int wid = threadIdx.x >> 6, lane = threadIdx.x & 63;
    float wl = Wl[lane], wr = Wr[lane];
    int wpb = blockDim.x >> 6;
    int stride = gridDim.x * wpb;
    for (int i = blockIdx.x * wpb + wid; i < n; i += stride) {
        float hv = h[(size_t)i * HD + lane];
        float a = hv * wl;
        float c = hv * wr;
#pragma unroll
        for (int off = 32; off > 0; off >>= 1) {
            a += __shfl_xor(a, off);
            c += __shfl_xor(c, off);
        }
        if (lane == 0) {
            sb[i] = a;
            tb[i] = c;
        }
    }
}

__global__ void __launch_bounds__(256) last_k(const float* __restrict__ sb,
                                              const float* __restrict__ tb,
                                              const int* __restrict__ row_ptr,
                                              const int* __restrict__ col,
                                              const float* __restrict__ b_last,
                                              float* __restrict__ out, int n) {
    float b0 = b_last[0];
    int stride = gridDim.x * blockDim.x;
    for (int i = blockIdx.x * blockDim.x + threadIdx.x; i < n; i += stride) {
        int beg = row_ptr[i], end = row_ptr[i + 1];
        float acc = 0.f;
        for (int k = beg; k < end; ++k) acc += sb[col[k]];
        out[i] = 1.f / (1.f + expf(-(acc + tb[i] + b0)));
    }
}

extern "C" void kernel_launch(void* const* d_in, const int* in_sizes, int n_in,
                              void* d_out, int out_size, void* d_ws, size_t ws_size,
                              hipStream_t stream) {
    const float* x_gen = (const float*)d_in[0];
    const float* x_load = (const float*)d_in[1];
    const float* x_or = (const float*)d_in[2];
    const float* x_ex = (const float*)d_in[3];
    const int* edge = (const int*)d_in[4];
    const int* ptv = (const int*)d_in[5];
    const float* W_gen1 = (const float*)d_in[6];
    const float* b_gen1 = (const float*)d_in[7];
    const float* W_gen2 = (const float*)d_in[8];
    const float* b_gen2 = (const float*)d_in[9];
    const float* W_load1 = (const float*)d_in[10];
    const float* b_load1 = (const float*)d_in[11];
    const float* W_load2 = (const float*)d_in[12];
    const float* b_load2 = (const float*)d_in[13];
    const float* W_or1 = (const float*)d_in[14];
    const float* b_or1 = (const float*)d_in[15];
    const float* W_or2 = (const float*)d_in[16];
    const float* b_or2 = (const float*)d_in[17];
    const float* W_ex1 = (const float*)d_in[18];
    const float* b_ex1 = (const float*)d_in[19];
    const float* W_ex2 = (const float*)d_in[20];
    const float* b_ex2 = (const float*)d_in[21];
    const float* Wl_h = (const float*)d_in[22];
    const float* Wr_h = (const float*)d_in[23];
    const float* b_h = (const float*)d_in[24];
    const float* Wl_last = (const float*)d_in[25];
    const float* Wr_last = (const float*)d_in[26];
    const float* b_last = (const float*)d_in[27];

    int n_gen = in_sizes[0] / 3;
    int n_load = in_sizes[1] / 3;
    int n_or = in_sizes[2] / 6;
    int n_ex = in_sizes[3] / 6;
    int E_ = in_sizes[4] / 2;
    int N_ = in_sizes[5];
    const int* srcv = edge;        // row 0
    const int* dstv = edge + E_;   // row 1

    char* ws = (char*)d_ws;
    size_t off = 0;
    auto alloc = [&](size_t bytes) -> void* {
        void* p = ws + off;
        off = (off + bytes + 255) & ~(size_t)255;
        return p;
    };
    float* enc = (float*)alloc((size_t)N_ * HD * 4);  // reused as agg after gather
    float* hA = (float*)alloc((size_t)N_ * HD * 4);
    float* hB = (float*)alloc((size_t)N_ * HD * 4);
    int* counts = (int*)alloc((size_t)N_ * 4);
    int* row_ptr = (int*)alloc((size_t)(N_ + 1) * 4);
    int* pos = (int*)alloc((size_t)N_ * 4);
    int* bsum = (int*)alloc(256 * 4);
    int* csr_col = (int*)alloc((size_t)E_ * 4);
    float* sbuf = (float*)alloc((size_t)N_ * 4);
    float* tbuf = (float*)alloc((size_t)N_ * 4);
    float* agg = enc;  // alias: enc is dead after gather_k
    (void)ws_size;

    zero_i32<<<256, 256, 0, stream>>>(counts, N_);

    encode_k<3><<<(n_gen + 3) / 4, 256, 0, stream>>>(x_gen, W_gen1, b_gen1, W_gen2, b_gen2,
                                                     enc, n_gen);
    encode_k<3><<<(n_load + 3) / 4, 256, 0, stream>>>(x_load, W_load1, b_load1, W_load2, b_load2,
                                                      enc + (size_t)n_gen * HD, n_load);
    encode_k<6><<<(n_or + 3) / 4, 256, 0, stream>>>(x_or, W_or1, b_or1, W_or2, b_or2,
                                                    enc + (size_t)(n_gen + n_load) * HD, n_or);
    encode_k<6><<<(n_ex + 3) / 4, 256, 0, stream>>>(x_ex, W_ex1, b_ex1, W_ex2, b_ex2,
                                                    enc + (size_t)(n_gen + n_load + n_or) * HD, n_ex);

    gather_k<<<2048, 256, 0, stream>>>(enc, ptv, hA, N_);

    hist_k<<<2048, 256, 0, stream>>>(dstv, counts, E_);
    int nb = (N_ + CHUNK - 1) / CHUNK;
    scan1<<<nb, 256, 0, stream>>>(counts, bsum, N_);
    scan2<<<1, 64, 0, stream>>>(bsum, nb, row_ptr, N_);
    scan3<<<nb, 256, 0, stream>>>(counts, bsum, row_ptr, pos, N_);
    scatter_k<<<2048, 256, 0, stream>>>(srcv, dstv, pos, csr_col, E_);

    int ntiles = (N_ + 63) >> 6;
    int ggrid = ntiles < 512 ? ntiles : 512;
    float* cur = hA;
    float* nxt = hB;
    for (int l = 0; l < 7; ++l) {
        agg_k<<<4096, 256, 0, stream>>>(cur, agg, row_ptr, csr_col, N_);
        sage_gemm_tile<<<ggrid, 256, 0, stream>>>(agg, cur, nxt,
                                                  Wl_h + (size_t)l * HD * HD,
                                                  Wr_h + (size_t)l * HD * HD,
                                                  b_h + (size_t)l * HD, N_);
        float* t = cur;
        cur = nxt;
        nxt = t;
    }
    dot_k<<<1024, 256, 0, stream>>>(cur, Wl_last, Wr_last, sbuf, tbuf, N_);
    last_k<<<512, 256, 0, stream>>>(sbuf, tbuf, row_ptr, csr_col, b_last,
                                    (float*)d_out, N_);
}